// Round 12
// baseline (63.826 us; speedup 1.0000x reference)
//
#include <hip/hip_runtime.h>

#define NR_ACTIONS 64
#define VEC 512
#define BK 64               // K per chunk (8 chunks)
#define MAXB 2048           // fast-scan path size

typedef short bf16x8 __attribute__((ext_vector_type(8)));
typedef float f32x4  __attribute__((ext_vector_type(4)));

__device__ __forceinline__ ushort f2bf(float f) {
    union { float f; uint32_t u; } x; x.f = f;
    uint32_t r = x.u + 0x7FFFu + ((x.u >> 16) & 1u);   // RNE
    return (ushort)(r >> 16);
}
__device__ __forceinline__ uint32_t pack2(float a, float b) {
    return (uint32_t)f2bf(a) | ((uint32_t)f2bf(b) << 16);
}
// swizzled byte offset in an 8 KB chunk buffer: col 0..63, kl 0..63
// linear col*128 + kl*2, XOR'd so 16 col-strided b128 reads spread banks
__device__ __forceinline__ int bswz(int col, int kl) {
    return (col * 128 + kl * 2) ^ ((col & 7) << 4);
}

// reg-stage chunk ck: 4 float4/thread; thread t covers rows kq..kq+3, cols c0..c0+3
__device__ __forceinline__ void loadw(const float* __restrict__ Wa, int ck, int t,
                                      float4 wr[4]) {
    const float* p = Wa + (size_t)(ck * BK + (t & 15) * 4) * VEC + (t >> 4) * 4;
#pragma unroll
    for (int i = 0; i < 4; ++i) wr[i] = *(const float4*)(p + (size_t)i * VEC);
}
// cvt + transposed swizzled write: per col, b64 of 4 consecutive k
__device__ __forceinline__ void cvtwrite(const float4 wr[4], char* buf, int t) {
    const int kq = (t & 15) * 4;
    const int c0 = (t >> 4) * 4;
#pragma unroll
    for (int c = 0; c < 4; ++c) {
        uint2 p;
        p.x = pack2((&wr[0].x)[c], (&wr[1].x)[c]);
        p.y = pack2((&wr[2].x)[c], (&wr[3].x)[c]);
        *(uint2*)(buf + bswz(c0 + c, kq)) = p;
    }
}

// ordered wave-level ballot scan, window [w0,w0+64); returns group size
__device__ __forceinline__ int scan_win(const int* __restrict__ action, int batch,
                                        int a, int w0, int lane, ushort* slist) {
    int base = 0;
    for (int it = 0; it < batch; it += 64) {
        const int idx = it + lane;
        const bool hit = (idx < batch) && (action[idx] == a);
        const unsigned long long mk = __ballot(hit);
        const int rp = base + __popcll(mk & ((1ull << lane) - 1ull)) - w0;
        if (hit && rp >= 0 && rp < 64) slist[rp] = (ushort)idx;
        base += __popcll(mk);
    }
    return base;
}

// ---- single kernel: 512 blocks x 256 thr (2/CU). Block = (action, 64-col oct);
// wave owns 16 cols x up-to-64 rows. W reg-staged -> bf16 swizzled LDS dbuf;
// lgkm-only raw barriers (W loads stay in flight across them); A from fp32 v
// with in-reg cvt. No second kernel, no workspace. ----
__global__ __launch_bounds__(256) void block_gemm(
    const float* __restrict__ v, const int* __restrict__ action,
    const float* __restrict__ W, float* __restrict__ out, int batch)
{
    __shared__ __align__(16) char sB0[8192];
    __shared__ __align__(16) char sB1[8192];
    __shared__ ushort slist[64];
    __shared__ int    smc;

    const int h    = blockIdx.x;
    const int l    = (h & 7) * 64 + (h >> 3);   // XCD-bijective (512 = 8*64)
    const int a    = l >> 3;                    // 8 whole actions per XCD
    const int j0   = (l & 7) * 64;              // column octant
    const int tid  = threadIdx.x;
    const int lane = tid & 63;
    const int wv   = tid >> 6;
    const int li   = lane & 15;
    const int g    = lane >> 4;

    const float* Wa = W + (size_t)a * VEC * VEC + j0;
    const bool fast = (batch == MAXB);

    // wave0: independent action loads first (vmcnt in-order per wave)
    int av[32];
    if (wv == 0 && fast) {
#pragma unroll
        for (int c = 0; c < 32; ++c) av[c] = action[c * 64 + lane];
    }

    float4 wrA[4], wrB[4];
    loadw(Wa, 0, tid, wrA);
    loadw(Wa, 1, tid, wrB);

    // wave0: ordered window-0 list (register-only ballot chain on fast path)
    if (wv == 0) {
        if (fast) {
            int base = 0;
#pragma unroll
            for (int c = 0; c < 32; ++c) {
                const bool hit = (av[c] == a);
                const unsigned long long mk = __ballot(hit);
                const int pos = base + __popcll(mk & ((1ull << lane) - 1ull));
                if (hit && pos < 64) slist[pos] = (ushort)(c * 64 + lane);
                base += __popcll(mk);
            }
            if (lane == 0) smc = base;
        } else {
            const int base = scan_win(action, batch, a, 0, lane, slist);
            if (lane == 0) smc = base;
        }
    }

    // prologue: chunks 0,1 -> LDS; chunks 2,3 left IN FLIGHT across the barrier
    cvtwrite(wrA, sB0, tid);        // waits only wrA's 4 loads
    loadw(Wa, 2, tid, wrA);
    cvtwrite(wrB, sB1, tid);
    loadw(Wa, 3, tid, wrB);
    asm volatile("s_waitcnt lgkmcnt(0)\ns_barrier" ::: "memory");

    const int m = smc;              // block-uniform
    if (m == 0) return;

    for (int wlo = 0; wlo < m; wlo += 64) {
        if (wlo > 0) {              // rare (m > 64): rescan + restage, full drain
            __syncthreads();
            if (wv == 0) scan_win(action, batch, a, wlo, lane, slist);
            __syncthreads();
            loadw(Wa, 0, tid, wrA);
            loadw(Wa, 1, tid, wrB);
            cvtwrite(wrA, sB0, tid);
            loadw(Wa, 2, tid, wrA);
            cvtwrite(wrB, sB1, tid);
            loadw(Wa, 3, tid, wrB);
            asm volatile("s_waitcnt lgkmcnt(0)\ns_barrier" ::: "memory");
        }
        const int mw  = min(64, m - wlo);
        const int nrb = (mw + 15) >> 4;

        int ridx[4];
#pragma unroll
        for (int rb = 0; rb < 4; ++rb) {
            const int rl = rb * 16 + li;
            ridx[rb] = slist[rl < mw ? rl : 0];   // clamp: discarded at store
        }

        f32x4 acc[4];
#pragma unroll
        for (int rb = 0; rb < 4; ++rb) acc[rb] = (f32x4){0.f, 0.f, 0.f, 0.f};

#pragma unroll
        for (int ck = 0; ck < 8; ++ck) {
            const char* bufc = (ck & 1) ? sB1 : sB0;
            // compute chunk ck; A-loads overlap MFMA; W[ck+2] arriving meanwhile
#pragma unroll
            for (int ks2 = 0; ks2 < 2; ++ks2) {
                const bf16x8 bf =
                    *(const bf16x8*)(bufc + bswz(wv * 16 + li, ks2 * 32 + g * 8));
#pragma unroll
                for (int rb = 0; rb < 4; ++rb) {
                    if (rb < nrb) {
                        const float* ap =
                            v + (size_t)ridx[rb] * VEC + ck * 64 + ks2 * 32 + g * 8;
                        const float4 f0 = *(const float4*)(ap);
                        const float4 f1 = *(const float4*)(ap + 4);
                        union { uint32_t u[4]; bf16x8 s; } au;
                        au.u[0] = pack2(f0.x, f0.y); au.u[1] = pack2(f0.z, f0.w);
                        au.u[2] = pack2(f1.x, f1.y); au.u[3] = pack2(f1.z, f1.w);
                        acc[rb] = __builtin_amdgcn_mfma_f32_16x16x32_bf16(
                            au.s, bf, acc[rb], 0, 0, 0);
                    }
                }
            }
            // reads of buf[ck&1] settled -> safe to overwrite with chunk ck+2
            asm volatile("s_waitcnt lgkmcnt(0)\ns_barrier" ::: "memory");
            if (ck < 6) {
                if (ck & 1) {
                    cvtwrite(wrB, sB1, tid);          // chunk ck+2
                    if (ck < 4) loadw(Wa, ck + 4, tid, wrB);
                } else {
                    cvtwrite(wrA, sB0, tid);          // chunk ck+2
                    if (ck < 4) loadw(Wa, ck + 4, tid, wrA);
                }
            }
        }

        // stores: D layout col=lane&15, row=(lane>>4)*4+q (m89-verified)
        const int colg = j0 + wv * 16 + li;
#pragma unroll
        for (int rb = 0; rb < 4; ++rb) {
            if (rb < nrb) {
#pragma unroll
                for (int q = 0; q < 4; ++q) {
                    const int row = rb * 16 + g * 4 + q;
                    if (row < mw)
                        out[(size_t)slist[row] * VEC + colg] = acc[rb][q];
                }
            }
        }
    }
}

// ---- fallback for batch > MAXB: naive per-row ----
__global__ void naive_vm(const float* __restrict__ v, const float* __restrict__ W,
                         const int* __restrict__ action, float* __restrict__ out) {
    const int b = blockIdx.x;
    const int a = action[b];
    const float* wbase = W + (size_t)a * VEC * VEC;
    const float* vb = v + (size_t)b * VEC;
    const int j = threadIdx.x;
    float acc0 = 0.f, acc1 = 0.f;
    for (int k = 0; k < VEC; ++k) {
        const float vk = vb[k];
        acc0 = fmaf(vk, wbase[(size_t)k * VEC + j], acc0);
        acc1 = fmaf(vk, wbase[(size_t)k * VEC + j + 256], acc1);
    }
    out[(size_t)b * VEC + j] = acc0;
    out[(size_t)b * VEC + j + 256] = acc1;
}

extern "C" void kernel_launch(void* const* d_in, const int* in_sizes, int n_in,
                              void* d_out, int out_size, void* d_ws, size_t ws_size,
                              hipStream_t stream) {
    const float* v      = (const float*)d_in[0];
    const int*   action = (const int*)d_in[1];
    const float* W      = (const float*)d_in[2];
    float* out = (float*)d_out;
    const int batch = in_sizes[1];
    if (batch <= 0) return;

    if (batch > MAXB) {
        naive_vm<<<batch, 256, 0, stream>>>(v, W, action, out);
        return;
    }
    block_gemm<<<NR_ACTIONS * 8, 256, 0, stream>>>(v, action, W, out, batch);
}

// Round 13
// 36.379 us; speedup vs baseline: 1.7544x; 1.7544x over previous
//
#include <hip/hip_runtime.h>
#include <hip/hip_bf16.h>

#define NR_ACTIONS 64
#define VEC 512
#define MAXB 2048

typedef short bf16x8 __attribute__((ext_vector_type(8)));
typedef float f32x4  __attribute__((ext_vector_type(4)));

// single-instruction packed cvt (compiler emits v_cvt_pk_bf16_f32).
// Pair order is applied identically to A and B, so any low/high convention
// yields a consistent k-permutation -> exact contraction.
__device__ __forceinline__ uint32_t cvt2(float a, float b) {
    union { __hip_bfloat162 h; uint32_t u; } r;
    r.h = __float22bfloat162_rn(float2{a, b});
    return r.u;
}

// LDS chunk buffer: 32 cols x 256 k bf16 (16 KB), XOR-swizzled
__device__ __forceinline__ int bswz(int col, int kl) {
    return (col * 512 + kl * 2) ^ ((col & 7) << 4);
}

// stage chunk: 256k x 32cols fp32; thread covers k=q*8..+7, cols col4..+3
__device__ __forceinline__ void loadreg(const float* __restrict__ base, int tid,
                                        float4 wr[8]) {
    const float* p = base + (size_t)((tid >> 3) * 8) * VEC + (tid & 7) * 4;
#pragma unroll
    for (int i = 0; i < 8; ++i) wr[i] = *(const float4*)(p + (size_t)i * VEC);
}
__device__ __forceinline__ void cvtwrite(const float4 wr[8], char* buf, int tid) {
    const int q = tid >> 3, col4 = (tid & 7) * 4;
#pragma unroll
    for (int ii = 0; ii < 2; ++ii)
#pragma unroll
        for (int c = 0; c < 4; ++c) {
            uint2 p;
            p.x = cvt2((&wr[ii * 4 + 0].x)[c], (&wr[ii * 4 + 1].x)[c]);
            p.y = cvt2((&wr[ii * 4 + 2].x)[c], (&wr[ii * 4 + 3].x)[c]);
            *(uint2*)(buf + bswz(col4 + c, q * 8 + ii * 4)) = p;
        }
}

// one wave-quadrant (16 cols x 2 row-blocks) against one staged chunk
__device__ __forceinline__ void compute_chunk(
    const char* buf, const float* __restrict__ v, int kbase,
    int ch, int li, int g, int r0, int r1, bool act0, bool act1,
    f32x4& acc0, f32x4& acc1)
{
#pragma unroll
    for (int ks = 0; ks < 8; ++ks) {
        const bf16x8 bf = *(const bf16x8*)(buf + bswz(ch * 16 + li, ks * 32 + g * 8));
        if (act0) {
            const float* ap = v + (size_t)r0 * VEC + kbase + ks * 32 + g * 8;
            const float4 f0 = *(const float4*)ap;
            const float4 f1 = *(const float4*)(ap + 4);
            union { uint32_t u[4]; bf16x8 s; } au;
            au.u[0] = cvt2(f0.x, f0.y); au.u[1] = cvt2(f0.z, f0.w);
            au.u[2] = cvt2(f1.x, f1.y); au.u[3] = cvt2(f1.z, f1.w);
            acc0 = __builtin_amdgcn_mfma_f32_16x16x32_bf16(au.s, bf, acc0, 0, 0, 0);
        }
        if (act1) {
            const float* ap = v + (size_t)r1 * VEC + kbase + ks * 32 + g * 8;
            const float4 f0 = *(const float4*)ap;
            const float4 f1 = *(const float4*)(ap + 4);
            union { uint32_t u[4]; bf16x8 s; } au;
            au.u[0] = cvt2(f0.x, f0.y); au.u[1] = cvt2(f0.z, f0.w);
            au.u[2] = cvt2(f1.x, f1.y); au.u[3] = cvt2(f1.z, f1.w);
            acc1 = __builtin_amdgcn_mfma_f32_16x16x32_bf16(au.s, bf, acc1, 0, 0, 0);
        }
    }
}

// ---- single kernel: 512 blocks x 256 thr (2/CU). Block = (action b&63, 64 cols
// = two 32-col tiles). 4 K-chunks pipelined through 2x16KB swizzled bf16 LDS;
// lgkm-only barriers (W loads stay in flight across them); A cvt'd in-register
// with v_cvt_pk. Default blockIdx->XCD mapping makes all 8 blocks of an action
// share one XCD's L2. ----
__global__ __launch_bounds__(256, 2) void persistent_gemm(
    const float* __restrict__ v, const int* __restrict__ action,
    const float* __restrict__ W, float* __restrict__ out, int batch)
{
    __shared__ __align__(16) char sB0[16384];
    __shared__ __align__(16) char sB1[16384];
    __shared__ ushort slist[MAXB];
    __shared__ int    smc;

    const int b    = blockIdx.x;
    const int a    = b & 63;
    const int cg   = b >> 6;              // 0..7
    const int tid  = threadIdx.x;
    const int lane = tid & 63;
    const int wv   = tid >> 6;
    const int li   = lane & 15;
    const int g    = lane >> 4;
    const int rh   = wv & 1;              // row-half of quadrant
    const int ch   = wv >> 1;             // col-half of quadrant

    const float* Wa = W + (size_t)a * VEC * VEC;
    const int j0t0 = cg * 32;
    const int j0t1 = (cg + 8) * 32;
    const bool fast = (batch == MAXB);

    // wave0: independent action loads first (vmcnt in-order per wave)
    int av[32];
    if (wv == 0 && fast) {
#pragma unroll
        for (int c = 0; c < 32; ++c) av[c] = action[c * 64 + lane];
    }

    // prologue: chunk0 staged, chunk1 loads left in flight
    float4 wrA[8], wrB[8];
    loadreg(Wa + j0t0, tid, wrA);                  // chunk0 = tile0 lo-K
    cvtwrite(wrA, sB0, tid);
    loadreg(Wa + 256 * VEC + j0t0, tid, wrB);      // chunk1 = tile0 hi-K

    // wave0: ordered full-group list (register-only ballot chain on fast path)
    if (wv == 0) {
        int base = 0;
        if (fast) {
#pragma unroll
            for (int c = 0; c < 32; ++c) {
                const bool hit = (av[c] == a);
                const unsigned long long mk = __ballot(hit);
                const int pos = base + __popcll(mk & ((1ull << lane) - 1ull));
                if (hit) slist[pos] = (ushort)(c * 64 + lane);
                base += __popcll(mk);
            }
        } else {
            for (int it = 0; it < batch; it += 64) {
                const int idx = it + lane;
                const bool hit = (idx < batch) && (action[idx] == a);
                const unsigned long long mk = __ballot(hit);
                const int pos = base + __popcll(mk & ((1ull << lane) - 1ull));
                if (hit && pos < MAXB) slist[pos] = (ushort)idx;
                base += __popcll(mk);
            }
        }
        if (lane == 0) smc = base;
    }

    asm volatile("s_waitcnt lgkmcnt(0)\ns_barrier" ::: "memory");
    const int m = smc;                    // block-uniform
    if (m == 0) return;                   // uniform exit

    const bool act0 = (rh * 16) < m;
    const bool act1 = (32 + rh * 16) < m;
    const int  row0 = rh * 16 + li;
    const int  row1 = 32 + rh * 16 + li;
    const int  r0   = slist[row0 < m ? row0 : 0];   // clamp: discarded at store
    const int  r1   = slist[row1 < m ? row1 : 0];

    f32x4 acc0 = {0.f, 0.f, 0.f, 0.f}, acc1 = {0.f, 0.f, 0.f, 0.f};

    // c=0: tile0 lo-K
    compute_chunk(sB0, v, 0, ch, li, g, r0, r1, act0, act1, acc0, acc1);
    cvtwrite(wrB, sB1, tid);                       // chunk1 -> buf1
    loadreg(Wa + j0t1, tid, wrA);                  // chunk2 = tile1 lo-K
    asm volatile("s_waitcnt lgkmcnt(0)\ns_barrier" ::: "memory");
    // c=1: tile0 hi-K
    compute_chunk(sB1, v, 256, ch, li, g, r0, r1, act0, act1, acc0, acc1);
    cvtwrite(wrA, sB0, tid);                       // chunk2 -> buf0
    loadreg(Wa + 256 * VEC + j0t1, tid, wrB);      // chunk3 = tile1 hi-K
    asm volatile("s_waitcnt lgkmcnt(0)\ns_barrier" ::: "memory");
    // store tile0 (D layout: col=lane&15, row=(lane>>4)*4+q; m89-verified)
    {
        const int colg = j0t0 + ch * 16 + li;
#pragma unroll
        for (int q = 0; q < 4; ++q) {
            const int ra = rh * 16 + g * 4 + q;
            if (ra < m) out[(size_t)slist[ra] * VEC + colg] = acc0[q];
            const int rb = 32 + rh * 16 + g * 4 + q;
            if (rb < m) out[(size_t)slist[rb] * VEC + colg] = acc1[q];
        }
    }
    acc0 = (f32x4){0.f, 0.f, 0.f, 0.f};
    acc1 = (f32x4){0.f, 0.f, 0.f, 0.f};
    // c=2: tile1 lo-K
    compute_chunk(sB0, v, 0, ch, li, g, r0, r1, act0, act1, acc0, acc1);
    cvtwrite(wrB, sB1, tid);                       // chunk3 -> buf1
    asm volatile("s_waitcnt lgkmcnt(0)\ns_barrier" ::: "memory");
    // c=3: tile1 hi-K
    compute_chunk(sB1, v, 256, ch, li, g, r0, r1, act0, act1, acc0, acc1);
    {
        const int colg = j0t1 + ch * 16 + li;
#pragma unroll
        for (int q = 0; q < 4; ++q) {
            const int ra = rh * 16 + g * 4 + q;
            if (ra < m) out[(size_t)slist[ra] * VEC + colg] = acc0[q];
            const int rb = 32 + rh * 16 + g * 4 + q;
            if (rb < m) out[(size_t)slist[rb] * VEC + colg] = acc1[q];
        }
    }

    // ---- rare path: m > 64 -> remaining windows, simple restaged loop ----
    for (int wlo = 64; wlo < m; wlo += 64) {
        const int mw = min(64, m - wlo);
        const bool f0 = (rh * 16) < mw, f1 = (32 + rh * 16) < mw;
        const int w0 = wlo + rh * 16 + li, w1 = wlo + 32 + rh * 16 + li;
        const int q0 = slist[w0 < m ? w0 : wlo];
        const int q1 = slist[w1 < m ? w1 : wlo];
#pragma unroll
        for (int tt = 0; tt < 2; ++tt) {
            const int jt = (cg + 8 * tt) * 32;
            f32x4 a0 = {0.f, 0.f, 0.f, 0.f}, a1 = {0.f, 0.f, 0.f, 0.f};
#pragma unroll
            for (int hh = 0; hh < 2; ++hh) {
                __syncthreads();          // prev reads done before overwrite
                float4 wr[8];
                loadreg(Wa + (size_t)hh * 256 * VEC + jt, tid, wr);
                cvtwrite(wr, sB0, tid);
                __syncthreads();
                compute_chunk(sB0, v, hh * 256, ch, li, g, q0, q1, f0, f1, a0, a1);
            }
            const int colg = jt + ch * 16 + li;
#pragma unroll
            for (int q = 0; q < 4; ++q) {
                const int ra = rh * 16 + g * 4 + q;
                if (ra < mw) out[(size_t)slist[wlo + ra] * VEC + colg] = a0[q];
                const int rb = 32 + rh * 16 + g * 4 + q;
                if (rb < mw) out[(size_t)slist[wlo + rb] * VEC + colg] = a1[q];
            }
        }
    }
}

// ---- fallback for batch > MAXB: naive per-row ----
__global__ void naive_vm(const float* __restrict__ v, const float* __restrict__ W,
                         const int* __restrict__ action, float* __restrict__ out) {
    const int b = blockIdx.x;
    const int a = action[b];
    const float* wbase = W + (size_t)a * VEC * VEC;
    const float* vb = v + (size_t)b * VEC;
    const int j = threadIdx.x;
    float acc0 = 0.f, acc1 = 0.f;
    for (int k = 0; k < VEC; ++k) {
        const float vk = vb[k];
        acc0 = fmaf(vk, wbase[(size_t)k * VEC + j], acc0);
        acc1 = fmaf(vk, wbase[(size_t)k * VEC + j + 256], acc1);
    }
    out[(size_t)b * VEC + j] = acc0;
    out[(size_t)b * VEC + j + 256] = acc1;
}

extern "C" void kernel_launch(void* const* d_in, const int* in_sizes, int n_in,
                              void* d_out, int out_size, void* d_ws, size_t ws_size,
                              hipStream_t stream) {
    const float* v      = (const float*)d_in[0];
    const int*   action = (const int*)d_in[1];
    const float* W      = (const float*)d_in[2];
    float* out = (float*)d_out;
    const int batch = in_sizes[1];
    if (batch <= 0) return;

    if (batch > MAXB) {
        naive_vm<<<batch, 256, 0, stream>>>(v, W, action, out);
        return;
    }
    persistent_gemm<<<NR_ACTIONS * 8, 256, 0, stream>>>(v, action, W, out, batch);
}

// Round 14
// 33.173 us; speedup vs baseline: 1.9240x; 1.0967x over previous
//
#include <hip/hip_runtime.h>
#include <hip/hip_bf16.h>

#define NR_ACTIONS 64
#define VEC 512
#define MAXB 2048

typedef short bf16x8 __attribute__((ext_vector_type(8)));
typedef float f32x4  __attribute__((ext_vector_type(4)));

// single-instruction packed cvt (v_cvt_pk_bf16_f32); same pairing used for A and B
__device__ __forceinline__ uint32_t cvt2(float a, float b) {
    union { __hip_bfloat162 h; uint32_t u; } r;
    r.h = __float22bfloat162_rn(float2{a, b});
    return r.u;
}
// swizzled byte offset into the 16 KB persistent tile: [col 0..15][k 0..511] bf16
__device__ __forceinline__ int bswz(int col, int kl) {
    return (col * 1024 + kl * 2) ^ ((col & 7) << 4);
}

// ---- main: 2048 blocks x 64 threads (1 wave) = (action, 16-col tile).
// ZERO barriers, zero shared-flag sync: all deps wave-local (counted vmcnt/lgkm).
// W tile staged once into persistent LDS; window loop covers ALL rows. ----
__global__ __launch_bounds__(64) void wave_gemm(
    const float* __restrict__ v, const int* __restrict__ action,
    const float* __restrict__ W, float* __restrict__ out, int batch)
{
    __shared__ __align__(16) char   sW[16 * 1024];   // bf16 [16 cols][512 k], swizzled
    __shared__ ushort slist[MAXB];                   // full ordered group list

    const int h  = blockIdx.x;
    const int l  = (h & 7) * ((int)gridDim.x >> 3) + (h >> 3);  // XCD-bijective
    const int a  = l >> 5;                 // 8 whole actions per XCD
    const int j0 = (l & 31) * 16;          // column tile
    const int lane = threadIdx.x;
    const int li = lane & 15, g = lane >> 4;

    const float* Wa = W + (size_t)a * VEC * VEC + j0;
    const bool fast = (batch == MAXB);

    // 1) issue the 32 action loads first (oldest in vmcnt queue -> land first)
    int av[32];
    if (fast) {
#pragma unroll
        for (int c = 0; c < 32; ++c) av[c] = action[c * 64 + lane];
    }

    // 2) issue W chunks 0,1 (chunk = 128k x 16c fp32; 8 float4/lane each)
    const int col4 = (lane & 3) * 4;
    const int kr0  = (lane >> 2) * 8;
    float4 w0r[8], w1r[8];
#pragma unroll
    for (int i = 0; i < 8; ++i)
        w0r[i] = *(const float4*)(Wa + (size_t)(kr0 + i) * VEC + col4);
#pragma unroll
    for (int i = 0; i < 8; ++i)
        w1r[i] = *(const float4*)(Wa + (size_t)(128 + kr0 + i) * VEC + col4);

    // 3) scan -> slist + m, register-only ballot chain (every lane ends with m)
    int m = 0;
    if (fast) {
#pragma unroll
        for (int c = 0; c < 32; ++c) {
            const bool hit = (av[c] == a);
            const unsigned long long mk = __ballot(hit);
            const int pos = m + __popcll(mk & ((1ull << lane) - 1ull));
            if (hit) slist[pos] = (ushort)(c * 64 + lane);
            m += __popcll(mk);
        }
    } else {
        for (int it = 0; it < batch; it += 64) {
            const int idx = it + lane;
            const bool hit = (idx < batch) && (action[idx] == a);
            const unsigned long long mk = __ballot(hit);
            const int pos = m + __popcll(mk & ((1ull << lane) - 1ull));
            if (hit && pos < MAXB) slist[pos] = (ushort)idx;
            m += __popcll(mk);
        }
    }
    if (m == 0) return;   // wave-uniform

    // 4) stage pipeline: cw(c0); issue c2; cw(c1); issue c3; cw(c2); cw(c3)
#define CW(wr, ck)                                                          \
    {                                                                       \
        _Pragma("unroll")                                                   \
        for (int c = 0; c < 4; ++c) {                                       \
            uint4 p;                                                        \
            p.x = cvt2((&wr[0].x)[c], (&wr[1].x)[c]);                       \
            p.y = cvt2((&wr[2].x)[c], (&wr[3].x)[c]);                       \
            p.z = cvt2((&wr[4].x)[c], (&wr[5].x)[c]);                       \
            p.w = cvt2((&wr[6].x)[c], (&wr[7].x)[c]);                       \
            *(uint4*)(sW + bswz(col4 + c, (ck) * 128 + kr0)) = p;           \
        }                                                                   \
    }
    CW(w0r, 0);
    float4 w2r[8];
#pragma unroll
    for (int i = 0; i < 8; ++i)
        w2r[i] = *(const float4*)(Wa + (size_t)(256 + kr0 + i) * VEC + col4);
    CW(w1r, 1);
    float4 w3r[8];
#pragma unroll
    for (int i = 0; i < 8; ++i)
        w3r[i] = *(const float4*)(Wa + (size_t)(384 + kr0 + i) * VEC + col4);
    CW(w2r, 2);
    CW(w3r, 3);
#undef CW

    // 5) window loop: 16 rows x 16 cols per iteration against the resident tile
    for (int w0 = 0; w0 < m; w0 += 16) {
        const int mw = min(16, m - w0);
        const int rl = w0 + li;
        const int ridx = slist[rl < m ? rl : w0];    // clamp: discarded at store
        const float* ap = v + (size_t)ridx * VEC + g * 8;

        // gather + cvt all 16 A-fragments (loads pipeline under cvt chain)
        bf16x8 af[16];
#pragma unroll
        for (int ks = 0; ks < 16; ++ks) {
            const float4 f0 = *(const float4*)(ap + ks * 32);
            const float4 f1 = *(const float4*)(ap + ks * 32 + 4);
            union { uint32_t u[4]; bf16x8 s; } au;
            au.u[0] = cvt2(f0.x, f0.y); au.u[1] = cvt2(f0.z, f0.w);
            au.u[2] = cvt2(f1.x, f1.y); au.u[3] = cvt2(f1.z, f1.w);
            af[ks] = au.s;
        }
        f32x4 acc = {0.f, 0.f, 0.f, 0.f};
#pragma unroll
        for (int ks = 0; ks < 16; ++ks) {
            const bf16x8 bf = *(const bf16x8*)(sW + bswz(li, ks * 32 + g * 8));
            acc = __builtin_amdgcn_mfma_f32_16x16x32_bf16(af[ks], bf, acc, 0, 0, 0);
        }
        // D layout: col=lane&15, row=(lane>>4)*4+q (m89-verified)
#pragma unroll
        for (int q = 0; q < 4; ++q) {
            const int row = g * 4 + q;
            if (row < mw)
                out[(size_t)slist[w0 + row] * VEC + j0 + li] = acc[q];
        }
    }
}

// ---- fallback for batch > MAXB: naive per-row ----
__global__ void naive_vm(const float* __restrict__ v, const float* __restrict__ W,
                         const int* __restrict__ action, float* __restrict__ out) {
    const int b = blockIdx.x;
    const int a = action[b];
    const float* wbase = W + (size_t)a * VEC * VEC;
    const float* vb = v + (size_t)b * VEC;
    const int j = threadIdx.x;
    float acc0 = 0.f, acc1 = 0.f;
    for (int k = 0; k < VEC; ++k) {
        const float vk = vb[k];
        acc0 = fmaf(vk, wbase[(size_t)k * VEC + j], acc0);
        acc1 = fmaf(vk, wbase[(size_t)k * VEC + j + 256], acc1);
    }
    out[(size_t)b * VEC + j] = acc0;
    out[(size_t)b * VEC + j + 256] = acc1;
}

extern "C" void kernel_launch(void* const* d_in, const int* in_sizes, int n_in,
                              void* d_out, int out_size, void* d_ws, size_t ws_size,
                              hipStream_t stream) {
    const float* v      = (const float*)d_in[0];
    const int*   action = (const int*)d_in[1];
    const float* W      = (const float*)d_in[2];
    float* out = (float*)d_out;
    const int batch = in_sizes[1];
    if (batch <= 0) return;

    if (batch > MAXB) {
        naive_vm<<<batch, 256, 0, stream>>>(v, W, action, out);
        return;
    }
    wave_gemm<<<NR_ACTIONS * 32, 64, 0, stream>>>(v, action, W, out, batch);
}

// Round 15
// 24.859 us; speedup vs baseline: 2.5676x; 1.3345x over previous
//
#include <hip/hip_runtime.h>
#include <hip/hip_bf16.h>

#define NR_ACTIONS 64
#define VEC 512
#define MAXB 2048

typedef short bf16x8 __attribute__((ext_vector_type(8)));
typedef float f32x4  __attribute__((ext_vector_type(4)));

// single-instruction packed cvt (v_cvt_pk_bf16_f32); identical pairing on A and B
__device__ __forceinline__ uint32_t cvt2(float a, float b) {
    union { __hip_bfloat162 h; uint32_t u; } r;
    r.h = __float22bfloat162_rn(float2{a, b});
    return r.u;
}
// A-tile LDS byte offset: row 0..15 (1 KB/row), kbyte 16B-granular, XOR-swizzled
// read pattern (16 lanes = 16 rows, same kbyte) spreads to all 32 banks, 2-way = free
__device__ __forceinline__ int aswz(int row, int kbyte) {
    return row * 1024 + (kbyte ^ ((row & 7) << 4));
}

// ---- main: 512 blocks x 256 thr (2/CU). Block = (action, 64-col octant).
// 4 waves share one 16-row A-window in LDS (v-rereads cut 4x); each wave's
// 16-col B-tile lives in 64 VGPRs, loaded ONCE from W (line-perfect strided
// scalar loads -> W read exactly once). A double-buffered in regs across
// windows. Total CU-load traffic ~112 MB -> ~17 us at the measured
// ~10.5 B/cy/CU load-return wall. ----
__global__ __launch_bounds__(256) void octant_gemm(
    const float* __restrict__ v, const int* __restrict__ action,
    const float* __restrict__ W, float* __restrict__ out, int batch)
{
    __shared__ __align__(16) char sA[16 * 1024];   // bf16 [16 rows][512 k], swizzled
    __shared__ ushort slist[MAXB];
    __shared__ int    smc;

    const int b    = blockIdx.x;
    const int a    = b & 63;        // b % 8 == a % 8 -> all 8 octants of an action
    const int oct  = b >> 6;        //   share one XCD's L2 (default round-robin)
    const int tid  = threadIdx.x;
    const int lane = tid & 63;
    const int wv   = tid >> 6;
    const int li   = lane & 15;
    const int g    = lane >> 4;
    const int colg = oct * 64 + wv * 16 + li;      // this lane's output column

    const float* Wa = W + (size_t)a * VEC * VEC;
    const bool fast = (batch == MAXB);

    // ---- wave0: action loads + ordered ballot scan (before any B loads) ----
    if (wv == 0) {
        int m0 = 0;
        if (fast) {
            int av[32];
#pragma unroll
            for (int c = 0; c < 32; ++c) av[c] = action[c * 64 + lane];
#pragma unroll
            for (int c = 0; c < 32; ++c) {
                const bool hit = (av[c] == a);
                const unsigned long long mk = __ballot(hit);
                const int pos = m0 + __popcll(mk & ((1ull << lane) - 1ull));
                if (hit) slist[pos] = (ushort)(c * 64 + lane);
                m0 += __popcll(mk);
            }
        } else {
            for (int it = 0; it < batch; it += 64) {
                const int idx = it + lane;
                const bool hit = (idx < batch) && (action[idx] == a);
                const unsigned long long mk = __ballot(hit);
                const int pos = m0 + __popcll(mk & ((1ull << lane) - 1ull));
                if (hit && pos < MAXB) slist[pos] = (ushort)idx;
                m0 += __popcll(mk);
            }
        }
        if (lane == 0) smc = m0;
    }
    __syncthreads();                 // slist/smc published (B is wave-private)
    const int m = smc;               // block-uniform
    if (m == 0) return;

    const int arow = tid >> 4;       // A-stage: this thread's row (0..15)
    const int akc  = tid & 15;       //          and 32-float k-chunk

    // ---- prefetch window-0 A rows (issued before the B flood) ----
    float4 pA[8], pB[8];
    {
        const int ridx = slist[arow < m ? arow : 0];
        const float* ap = v + (size_t)ridx * VEC + akc * 32;
#pragma unroll
        for (int i = 0; i < 8; ++i) pA[i] = *(const float4*)(ap + i * 4);
    }

    // ---- B-stage: 16 frags x 8 strided scalar loads, cvt_pk, regs only.
    // Lane (li,g) reads W[ks*32+g*8+e][colg]; each 64B line fully consumed
    // by one quarter-wave -> W streamed exactly once, no LDS. ----
    bf16x8 Bf[16];
#pragma unroll
    for (int ks = 0; ks < 16; ++ks) {
        const float* wp = Wa + (size_t)(ks * 32 + g * 8) * VEC + colg;
        float t[8];
#pragma unroll
        for (int e = 0; e < 8; ++e) t[e] = wp[(size_t)e * VEC];
        union { uint32_t u[4]; bf16x8 s; } bu;
        bu.u[0] = cvt2(t[0], t[1]);
        bu.u[1] = cvt2(t[2], t[3]);
        bu.u[2] = cvt2(t[4], t[5]);
        bu.u[3] = cvt2(t[6], t[7]);
        Bf[ks] = bu.s;
    }

    // ---- window loop: 16 shared rows/iteration vs 4 resident B-tiles ----
    int w0 = 0;
    while (true) {
        // stage A window: cvt_pk + swizzled b128 writes (pA loads auto-waited)
#pragma unroll
        for (int i = 0; i < 4; ++i) {
            uint4 p;
            p.x = cvt2(pA[2 * i].x, pA[2 * i].y);
            p.y = cvt2(pA[2 * i].z, pA[2 * i].w);
            p.z = cvt2(pA[2 * i + 1].x, pA[2 * i + 1].y);
            p.w = cvt2(pA[2 * i + 1].z, pA[2 * i + 1].w);
            *(uint4*)(sA + aswz(arow, akc * 64 + i * 16)) = p;
        }
        __syncthreads();             // A window visible to all waves

        if (w0 + 16 < m) {           // prefetch next window under the MFMAs
            const int rl = w0 + 16 + arow;
            const int ridx = slist[rl < m ? rl : 0];
            const float* ap = v + (size_t)ridx * VEC + akc * 32;
#pragma unroll
            for (int i = 0; i < 8; ++i) pB[i] = *(const float4*)(ap + i * 4);
        }

        f32x4 acc = {0.f, 0.f, 0.f, 0.f};
#pragma unroll
        for (int ks = 0; ks < 16; ++ks) {
            // af elements: k = ks*32 + g*8 + e  == Bf's k-map -> exact contraction
            const bf16x8 af = *(const bf16x8*)(sA + aswz(li, ks * 64 + g * 16));
            acc = __builtin_amdgcn_mfma_f32_16x16x32_bf16(af, Bf[ks], acc, 0, 0, 0);
        }
        // D layout: col=lane&15, row=(lane>>4)*4+q (m89-verified)
#pragma unroll
        for (int q = 0; q < 4; ++q) {
            const int row = w0 + g * 4 + q;
            if (row < m)
                out[(size_t)slist[row] * VEC + colg] = acc[q];
        }

        w0 += 16;
        if (w0 >= m) break;          // uniform
        __syncthreads();             // all A reads done before overwrite
#pragma unroll
        for (int i = 0; i < 8; ++i) pA[i] = pB[i];
    }
}

// ---- fallback for batch > MAXB: naive per-row ----
__global__ void naive_vm(const float* __restrict__ v, const float* __restrict__ W,
                         const int* __restrict__ action, float* __restrict__ out) {
    const int b = blockIdx.x;
    const int a = action[b];
    const float* wbase = W + (size_t)a * VEC * VEC;
    const float* vb = v + (size_t)b * VEC;
    const int j = threadIdx.x;
    float acc0 = 0.f, acc1 = 0.f;
    for (int k = 0; k < VEC; ++k) {
        const float vk = vb[k];
        acc0 = fmaf(vk, wbase[(size_t)k * VEC + j], acc0);
        acc1 = fmaf(vk, wbase[(size_t)k * VEC + j + 256], acc1);
    }
    out[(size_t)b * VEC + j] = acc0;
    out[(size_t)b * VEC + j + 256] = acc1;
}

extern "C" void kernel_launch(void* const* d_in, const int* in_sizes, int n_in,
                              void* d_out, int out_size, void* d_ws, size_t ws_size,
                              hipStream_t stream) {
    const float* v      = (const float*)d_in[0];
    const int*   action = (const int*)d_in[1];
    const float* W      = (const float*)d_in[2];
    float* out = (float*)d_out;
    const int batch = in_sizes[1];
    if (batch <= 0) return;

    if (batch > MAXB) {
        naive_vm<<<batch, 256, 0, stream>>>(v, W, action, out);
        return;
    }
    octant_gemm<<<NR_ACTIONS * 8, 256, 0, stream>>>(v, action, W, out, batch);
}

// Round 16
// 20.939 us; speedup vs baseline: 3.0482x; 1.1872x over previous
//
#include <hip/hip_runtime.h>
#include <hip/hip_bf16.h>

#define NR_ACTIONS 64
#define VEC 512
#define MAXB 2048

typedef short bf16x8 __attribute__((ext_vector_type(8)));
typedef float f32x4  __attribute__((ext_vector_type(4)));

// single-instruction packed cvt (v_cvt_pk_bf16_f32); identical pairing on A and B
__device__ __forceinline__ uint32_t cvt2(float a, float b) {
    union { __hip_bfloat162 h; uint32_t u; } r;
    r.h = __float22bfloat162_rn(float2{a, b});
    return r.u;
}
// A-tile LDS byte offset: row 0..15 (1 KB/row), kbyte 16B-granular, XOR-swizzled;
// compute-read (16 lanes = 16 rows, same kbyte) lands 2-way per bank = free
__device__ __forceinline__ int aswz(int row, int kbyte) {
    return row * 1024 + (kbyte ^ ((row & 7) << 4));
}

// ---- main: 256 blocks x 512 thr (8 waves) = (action, 128-col half).
// 8 waves share one 16-row A-window in LDS (v-rereads cut 8x vs per-wave);
// each wave's 16-col B-tile lives in 64 VGPRs, loaded ONCE from W via
// line-perfect strided scalar loads. A double-buffered in regs across windows.
// Total CU-load traffic ~90 MB -> ~14 us at the ~10.5 B/cy/CU return wall. ----
__global__ __launch_bounds__(512) void half_gemm(
    const float* __restrict__ v, const int* __restrict__ action,
    const float* __restrict__ W, float* __restrict__ out, int batch)
{
    __shared__ __align__(16) char sA[16 * 1024];   // bf16 [16 rows][512 k], swizzled
    __shared__ ushort slist[MAXB];
    __shared__ int    smc;

    const int b    = blockIdx.x;
    const int a    = b & 63;        // b%8 == a%8 -> both halves + siblings of an
    const int half = b >> 6;        //   action share one XCD's L2 (0..3)
    const int tid  = threadIdx.x;
    const int lane = tid & 63;
    const int wv   = tid >> 6;      // 0..7
    const int li   = lane & 15;
    const int g    = lane >> 4;
    const int colg = half * 128 + wv * 16 + li;    // this lane's output column

    const float* Wa = W + (size_t)a * VEC * VEC;
    const bool fast = (batch == MAXB);

    // ---- wave0: action loads + ordered ballot scan (before any B loads) ----
    if (wv == 0) {
        int m0 = 0;
        if (fast) {
            int av[32];
#pragma unroll
            for (int c = 0; c < 32; ++c) av[c] = action[c * 64 + lane];
#pragma unroll
            for (int c = 0; c < 32; ++c) {
                const bool hit = (av[c] == a);
                const unsigned long long mk = __ballot(hit);
                const int pos = m0 + __popcll(mk & ((1ull << lane) - 1ull));
                if (hit) slist[pos] = (ushort)(c * 64 + lane);
                m0 += __popcll(mk);
            }
        } else {
            for (int it = 0; it < batch; it += 64) {
                const int idx = it + lane;
                const bool hit = (idx < batch) && (action[idx] == a);
                const unsigned long long mk = __ballot(hit);
                const int pos = m0 + __popcll(mk & ((1ull << lane) - 1ull));
                if (hit && pos < MAXB) slist[pos] = (ushort)idx;
                m0 += __popcll(mk);
            }
        }
        if (lane == 0) smc = m0;
    }
    __syncthreads();                 // slist/smc published (B is wave-private)
    const int m = smc;               // block-uniform
    if (m == 0) return;

    const int arow = tid >> 5;       // A-stage: this thread's row (0..15)
    const int akc  = tid & 31;       //          16-float k-chunk (0..31)

    // ---- prefetch window-0 A rows (issued before the B flood) ----
    float4 pA[4], pB[4];
    {
        const int ridx = slist[arow < m ? arow : 0];
        const float* ap = v + (size_t)ridx * VEC + akc * 16;
#pragma unroll
        for (int i = 0; i < 4; ++i) pA[i] = *(const float4*)(ap + i * 4);
    }

    // ---- B-stage: 16 frags x 8 strided scalar loads, cvt_pk, regs only.
    // Lane (li,g) reads W[ks*32+g*8+e][colg]; each 64B line fully consumed
    // by one quarter-wave -> W streamed exactly once, no LDS. ----
    bf16x8 Bf[16];
#pragma unroll
    for (int ks = 0; ks < 16; ++ks) {
        const float* wp = Wa + (size_t)(ks * 32 + g * 8) * VEC + colg;
        float t[8];
#pragma unroll
        for (int e = 0; e < 8; ++e) t[e] = wp[(size_t)e * VEC];
        union { uint32_t u[4]; bf16x8 s; } bu;
        bu.u[0] = cvt2(t[0], t[1]);
        bu.u[1] = cvt2(t[2], t[3]);
        bu.u[2] = cvt2(t[4], t[5]);
        bu.u[3] = cvt2(t[6], t[7]);
        Bf[ks] = bu.s;
    }

    // ---- window loop: 16 shared rows/iteration vs 8 resident B-tiles ----
    int w0 = 0;
    while (true) {
        // stage A window: cvt_pk + swizzled b128 writes (pA loads auto-waited)
        {
            uint4 p;
            p.x = cvt2(pA[0].x, pA[0].y); p.y = cvt2(pA[0].z, pA[0].w);
            p.z = cvt2(pA[1].x, pA[1].y); p.w = cvt2(pA[1].z, pA[1].w);
            *(uint4*)(sA + aswz(arow, akc * 32)) = p;
            p.x = cvt2(pA[2].x, pA[2].y); p.y = cvt2(pA[2].z, pA[2].w);
            p.z = cvt2(pA[3].x, pA[3].y); p.w = cvt2(pA[3].z, pA[3].w);
            *(uint4*)(sA + aswz(arow, akc * 32 + 16)) = p;
        }
        __syncthreads();             // A window visible to all waves

        if (w0 + 16 < m) {           // prefetch next window under the MFMAs
            const int rl = w0 + 16 + arow;
            const int ridx = slist[rl < m ? rl : 0];
            const float* ap = v + (size_t)ridx * VEC + akc * 16;
#pragma unroll
            for (int i = 0; i < 4; ++i) pB[i] = *(const float4*)(ap + i * 4);
        }

        f32x4 acc = {0.f, 0.f, 0.f, 0.f};
#pragma unroll
        for (int ks = 0; ks < 16; ++ks) {
            // af elements: k = ks*32 + g*8 + e  == Bf's k-map -> exact contraction
            const bf16x8 af = *(const bf16x8*)(sA + aswz(li, ks * 64 + g * 16));
            acc = __builtin_amdgcn_mfma_f32_16x16x32_bf16(af, Bf[ks], acc, 0, 0, 0);
        }
        // D layout: col=lane&15, row=(lane>>4)*4+q (m89-verified)
#pragma unroll
        for (int q = 0; q < 4; ++q) {
            const int row = w0 + g * 4 + q;
            if (row < m)
                out[(size_t)slist[row] * VEC + colg] = acc[q];
        }

        w0 += 16;
        if (w0 >= m) break;          // uniform
        __syncthreads();             // all A reads done before overwrite
#pragma unroll
        for (int i = 0; i < 4; ++i) pA[i] = pB[i];
    }
}

// ---- fallback for batch > MAXB: naive per-row ----
__global__ void naive_vm(const float* __restrict__ v, const float* __restrict__ W,
                         const int* __restrict__ action, float* __restrict__ out) {
    const int b = blockIdx.x;
    const int a = action[b];
    const float* wbase = W + (size_t)a * VEC * VEC;
    const float* vb = v + (size_t)b * VEC;
    const int j = threadIdx.x;
    float acc0 = 0.f, acc1 = 0.f;
    for (int k = 0; k < VEC; ++k) {
        const float vk = vb[k];
        acc0 = fmaf(vk, wbase[(size_t)k * VEC + j], acc0);
        acc1 = fmaf(vk, wbase[(size_t)k * VEC + j + 256], acc1);
    }
    out[(size_t)b * VEC + j] = acc0;
    out[(size_t)b * VEC + j + 256] = acc1;
}

extern "C" void kernel_launch(void* const* d_in, const int* in_sizes, int n_in,
                              void* d_out, int out_size, void* d_ws, size_t ws_size,
                              hipStream_t stream) {
    const float* v      = (const float*)d_in[0];
    const int*   action = (const int*)d_in[1];
    const float* W      = (const float*)d_in[2];
    float* out = (float*)d_out;
    const int batch = in_sizes[1];
    if (batch <= 0) return;

    if (batch > MAXB) {
        naive_vm<<<batch, 256, 0, stream>>>(v, W, action, out);
        return;
    }
    half_gemm<<<NR_ACTIONS * 4, 512, 0, stream>>>(v, action, W, out, batch);
}

// Round 17
// 20.597 us; speedup vs baseline: 3.0988x; 1.0166x over previous
//
#include <hip/hip_runtime.h>
#include <hip/hip_bf16.h>

#define NR_ACTIONS 64
#define VEC 512
#define MAXB 2048
#define WROWS 48

typedef short bf16x8 __attribute__((ext_vector_type(8)));
typedef float f32x4  __attribute__((ext_vector_type(4)));

// single-instruction packed cvt (v_cvt_pk_bf16_f32); identical pairing on A and B
__device__ __forceinline__ uint32_t cvt2(float a, float b) {
    union { __hip_bfloat162 h; uint32_t u; } r;
    r.h = __float22bfloat162_rn(float2{a, b});
    return r.u;
}
// A-tile LDS byte offset: row (1 KB/row), kbyte 16B-granular, XOR-swizzled;
// compute-read (16 lanes = 16 consecutive rows, same kbyte) = 2-way per bank = free
__device__ __forceinline__ int aswz(int row, int kbyte) {
    return row * 1024 + (kbyte ^ ((row & 7) << 4));
}

// ---- main: 256 blocks x 512 thr (8 waves) = (action, 128-col half), 1 block/CU.
// Straight-line common case (m <= 48): scan -> bar -> A-stage(48 rows, 48 KB LDS)
// -> B-stage(64 VGPR/wave, W read exactly once, line-perfect strided loads)
// -> bar (A publish only; B is wave-private dataflow) -> 3 MFMA tile-sets ->
// stores -> exit. Per-CU traffic ~330-360 KB -> ~13-14 us at the measured
// ~10.5 B/cy/CU load-return wall; this round shaves window/barrier overhead. ----
__global__ __launch_bounds__(512) void half_gemm48(
    const float* __restrict__ v, const int* __restrict__ action,
    const float* __restrict__ W, float* __restrict__ out, int batch)
{
    __shared__ __align__(16) char sA[WROWS * 1024];   // bf16 [48 rows][512 k], swizzled
    __shared__ ushort slist[MAXB];
    __shared__ int    smc;

    const int b    = blockIdx.x;
    const int a    = b & 63;        // b%8 == a%8 -> all 4 halves of an action
    const int half = b >> 6;        //   share one XCD's L2 (default round-robin)
    const int tid  = threadIdx.x;
    const int lane = tid & 63;
    const int wv   = tid >> 6;      // 0..7
    const int li   = lane & 15;
    const int g    = lane >> 4;
    const int colg = half * 128 + wv * 16 + li;

    const float* Wa = W + (size_t)a * VEC * VEC;
    const bool fast = (batch == MAXB);

    // ---- wave0: action loads + ordered ballot scan ----
    if (wv == 0) {
        int m0 = 0;
        if (fast) {
            int av[32];
#pragma unroll
            for (int c = 0; c < 32; ++c) av[c] = action[c * 64 + lane];
#pragma unroll
            for (int c = 0; c < 32; ++c) {
                const bool hit = (av[c] == a);
                const unsigned long long mk = __ballot(hit);
                const int pos = m0 + __popcll(mk & ((1ull << lane) - 1ull));
                if (hit) slist[pos] = (ushort)(c * 64 + lane);
                m0 += __popcll(mk);
            }
        } else {
            for (int it = 0; it < batch; it += 64) {
                const int idx = it + lane;
                const bool hit = (idx < batch) && (action[idx] == a);
                const unsigned long long mk = __ballot(hit);
                const int pos = m0 + __popcll(mk & ((1ull << lane) - 1ull));
                if (hit && pos < MAXB) slist[pos] = (ushort)idx;
                m0 += __popcll(mk);
            }
        }
        if (lane == 0) smc = m0;
    }
    __syncthreads();                 // slist/smc published
    const int m = smc;               // block-uniform
    if (m == 0) return;

    const int arow = tid >> 5;       // A-stage: base row (0..15), rows arow+16j
    const int akc  = tid & 31;       //          16-float k-chunk (0..31)

    // ---- A-stage window 0: rows 0..min(m,48) (small: <=192 B/thread) ----
#pragma unroll
    for (int j = 0; j < 3; ++j) {
        const int row = arow + 16 * j;
        if (row < m && row < WROWS) {
            const float* ap = v + (size_t)slist[row] * VEC + akc * 16;
            const float4 p0 = *(const float4*)(ap);
            const float4 p1 = *(const float4*)(ap + 4);
            const float4 p2 = *(const float4*)(ap + 8);
            const float4 p3 = *(const float4*)(ap + 12);
            uint4 q;
            q.x = cvt2(p0.x, p0.y); q.y = cvt2(p0.z, p0.w);
            q.z = cvt2(p1.x, p1.y); q.w = cvt2(p1.z, p1.w);
            *(uint4*)(sA + aswz(row, akc * 32)) = q;
            q.x = cvt2(p2.x, p2.y); q.y = cvt2(p2.z, p2.w);
            q.z = cvt2(p3.x, p3.y); q.w = cvt2(p3.z, p3.w);
            *(uint4*)(sA + aswz(row, akc * 32 + 16)) = q;
        }
    }

    // ---- B-stage: 16 frags x 8 strided scalar loads, cvt_pk, regs only.
    // Each 64B line fully consumed by a quarter-wave -> W streamed exactly once. ----
    bf16x8 Bf[16];
#pragma unroll
    for (int ks = 0; ks < 16; ++ks) {
        const float* wp = Wa + (size_t)(ks * 32 + g * 8) * VEC + colg;
        float t[8];
#pragma unroll
        for (int e = 0; e < 8; ++e) t[e] = wp[(size_t)e * VEC];
        union { uint32_t u[4]; bf16x8 s; } bu;
        bu.u[0] = cvt2(t[0], t[1]);
        bu.u[1] = cvt2(t[2], t[3]);
        bu.u[2] = cvt2(t[4], t[5]);
        bu.u[3] = cvt2(t[6], t[7]);
        Bf[ks] = bu.s;
    }

    __syncthreads();                 // A window visible (B needs no barrier)

    // ---- compute: 3 tile-sets, block-uniform guards; k-map A==B -> exact ----
    f32x4 acc0 = {0.f, 0.f, 0.f, 0.f};
#pragma unroll
    for (int ks = 0; ks < 16; ++ks) {
        const bf16x8 af = *(const bf16x8*)(sA + aswz(li, ks * 64 + g * 16));
        acc0 = __builtin_amdgcn_mfma_f32_16x16x32_bf16(af, Bf[ks], acc0, 0, 0, 0);
    }
    f32x4 acc1 = {0.f, 0.f, 0.f, 0.f};
    if (m > 16) {
#pragma unroll
        for (int ks = 0; ks < 16; ++ks) {
            const bf16x8 af = *(const bf16x8*)(sA + aswz(16 + li, ks * 64 + g * 16));
            acc1 = __builtin_amdgcn_mfma_f32_16x16x32_bf16(af, Bf[ks], acc1, 0, 0, 0);
        }
    }
    f32x4 acc2 = {0.f, 0.f, 0.f, 0.f};
    if (m > 32) {
#pragma unroll
        for (int ks = 0; ks < 16; ++ks) {
            const bf16x8 af = *(const bf16x8*)(sA + aswz(32 + li, ks * 64 + g * 16));
            acc2 = __builtin_amdgcn_mfma_f32_16x16x32_bf16(af, Bf[ks], acc2, 0, 0, 0);
        }
    }

    // ---- stores: D layout col=lane&15, row=(lane>>4)*4+q (m89-verified) ----
#pragma unroll
    for (int q = 0; q < 4; ++q) {
        const int r0 = g * 4 + q;
        if (r0 < m) out[(size_t)slist[r0] * VEC + colg] = acc0[q];
        const int r1 = 16 + g * 4 + q;
        if (r1 < m) out[(size_t)slist[r1] * VEC + colg] = acc1[q];
        const int r2 = 32 + g * 4 + q;
        if (r2 < m && r2 < WROWS) out[(size_t)slist[r2] * VEC + colg] = acc2[q];
    }

    // ---- rare path (m > 48, P ~ 0.3%): restage remaining windows ----
    for (int w0 = WROWS; w0 < m; w0 += WROWS) {
        __syncthreads();             // all sA reads done before overwrite
#pragma unroll
        for (int j = 0; j < 3; ++j) {
            const int row = arow + 16 * j;
            if (w0 + row < m && row < WROWS) {
                const float* ap = v + (size_t)slist[w0 + row] * VEC + akc * 16;
                const float4 p0 = *(const float4*)(ap);
                const float4 p1 = *(const float4*)(ap + 4);
                const float4 p2 = *(const float4*)(ap + 8);
                const float4 p3 = *(const float4*)(ap + 12);
                uint4 q;
                q.x = cvt2(p0.x, p0.y); q.y = cvt2(p0.z, p0.w);
                q.z = cvt2(p1.x, p1.y); q.w = cvt2(p1.z, p1.w);
                *(uint4*)(sA + aswz(row, akc * 32)) = q;
                q.x = cvt2(p2.x, p2.y); q.y = cvt2(p2.z, p2.w);
                q.z = cvt2(p3.x, p3.y); q.w = cvt2(p3.z, p3.w);
                *(uint4*)(sA + aswz(row, akc * 32 + 16)) = q;
            }
        }
        __syncthreads();
#pragma unroll
        for (int rb = 0; rb < 3; ++rb) {
            if (w0 + rb * 16 < m) {
                f32x4 acc = {0.f, 0.f, 0.f, 0.f};
#pragma unroll
                for (int ks = 0; ks < 16; ++ks) {
                    const bf16x8 af =
                        *(const bf16x8*)(sA + aswz(rb * 16 + li, ks * 64 + g * 16));
                    acc = __builtin_amdgcn_mfma_f32_16x16x32_bf16(af, Bf[ks], acc, 0, 0, 0);
                }
#pragma unroll
                for (int q = 0; q < 4; ++q) {
                    const int rr = w0 + rb * 16 + g * 4 + q;
                    if (rr < m && rb * 16 + g * 4 + q < WROWS)
                        out[(size_t)slist[rr] * VEC + colg] = acc[q];
                }
            }
        }
    }
}

// ---- fallback for batch > MAXB: naive per-row ----
__global__ void naive_vm(const float* __restrict__ v, const float* __restrict__ W,
                         const int* __restrict__ action, float* __restrict__ out) {
    const int b = blockIdx.x;
    const int a = action[b];
    const float* wbase = W + (size_t)a * VEC * VEC;
    const float* vb = v + (size_t)b * VEC;
    const int j = threadIdx.x;
    float acc0 = 0.f, acc1 = 0.f;
    for (int k = 0; k < VEC; ++k) {
        const float vk = vb[k];
        acc0 = fmaf(vk, wbase[(size_t)k * VEC + j], acc0);
        acc1 = fmaf(vk, wbase[(size_t)k * VEC + j + 256], acc1);
    }
    out[(size_t)b * VEC + j] = acc0;
    out[(size_t)b * VEC + j + 256] = acc1;
}

extern "C" void kernel_launch(void* const* d_in, const int* in_sizes, int n_in,
                              void* d_out, int out_size, void* d_ws, size_t ws_size,
                              hipStream_t stream) {
    const float* v      = (const float*)d_in[0];
    const int*   action = (const int*)d_in[1];
    const float* W      = (const float*)d_in[2];
    float* out = (float*)d_out;
    const int batch = in_sizes[1];
    if (batch <= 0) return;

    if (batch > MAXB) {
        naive_vm<<<batch, 256, 0, stream>>>(v, W, action, out);
        return;
    }
    half_gemm48<<<NR_ACTIONS * 4, 512, 0, stream>>>(v, action, W, out, batch);
}